// Round 1
// baseline (38.807 us; speedup 1.0000x reference)
//
#include <hip/hip_runtime.h>

typedef __attribute__((ext_vector_type(8))) short short8;   // bf16x8 MFMA operand
typedef __attribute__((ext_vector_type(4))) float floatx4;  // f32x4 MFMA accumulator

#define LOG2E 1.4426950408889634f

__device__ __forceinline__ unsigned short f2bf(float f) {
  unsigned int u = __float_as_uint(f);
  u += 0x7FFFu + ((u >> 16) & 1u);   // RNE
  return (unsigned short)(u >> 16);
}

// ---------------- prep kernel: convert/permute weights into d_ws ----------------
// ws layout (bytes):
//   Wp    [384][256] bf16 @ 0        (n' = d*64 + t, pre-scaled by -log2e)
//   fcw   [256][64]  bf16 @ 196608
//   leaf2 [64][64]   f32  @ 229376   (pairs: leaf[2i], leaf[2i+1]-leaf[2i])
//   b1    [384]      f32  @ 245760   (n'-permuted, pre-scaled by -log2e)
//   sb    [64]       f32  @ 247296   (gamma * rsqrt(var+eps))
//   ob    [64]       f32  @ 247552   (beta - mean*sb)
__global__ void prep_kernel(const float* __restrict__ W_dec,
                            const float* __restrict__ b_dec,
                            const float* __restrict__ leaf,
                            const float* __restrict__ bn_gamma,
                            const float* __restrict__ bn_beta,
                            const float* __restrict__ bn_mean,
                            const float* __restrict__ bn_var,
                            const float* __restrict__ fc_w,
                            unsigned short* __restrict__ Wp,
                            unsigned short* __restrict__ fcw,
                            float* __restrict__ leaf2,
                            float* __restrict__ b1,
                            float* __restrict__ sb,
                            float* __restrict__ ob)
{
  int idx = (int)blockIdx.x * 256 + (int)threadIdx.x;
  if (idx < 384 * 256) {
    int np = idx >> 8, k = idx & 255;
    int d = np >> 6, t = np & 63;
    Wp[idx] = f2bf(-LOG2E * W_dec[(t * 6 + d) * 256 + k]);
    return;
  }
  idx -= 384 * 256;
  if (idx < 256 * 64) { fcw[idx] = f2bf(fc_w[idx]); return; }
  idx -= 256 * 64;
  if (idx < 2048) {
    int t = idx >> 5, i = idx & 31;
    float a = leaf[t * 64 + 2 * i];
    float b = leaf[t * 64 + 2 * i + 1];
    leaf2[t * 64 + 2 * i]     = a;
    leaf2[t * 64 + 2 * i + 1] = b - a;
    return;
  }
  idx -= 2048;
  if (idx < 384) {
    int t = idx / 6, d = idx % 6;
    b1[d * 64 + t] = -LOG2E * b_dec[idx];
    return;
  }
  idx -= 384;
  if (idx < 64) {
    float s = bn_gamma[idx] * rsqrtf(bn_var[idx] + 1e-5f);
    sb[idx] = s;
    ob[idx] = bn_beta[idx] - bn_mean[idx] * s;
  }
}

// ---------------- main fused kernel ----------------
// grid 512 blocks x 256 threads; BM=64 rows/block; 4 waves, wave w owns trees [16w,16w+16)
__global__ __launch_bounds__(256, 2)
void node_main(const float* __restrict__ x,
               const unsigned short* __restrict__ Wp,
               const unsigned short* __restrict__ fcw,
               const float* __restrict__ leaf2,
               const float* __restrict__ b1g,
               const float* __restrict__ sbg,
               const float* __restrict__ obg,
               const float* __restrict__ fc_b,
               float* __restrict__ out)
{
  __shared__ unsigned short A_lds[64][264];   // x tile bf16, +8 pad -> 2-way (free) frag reads
  __shared__ float leaf_lds[64][68];          // leaf (a,delta) pairs, +4 pad
  __shared__ unsigned short A2_lds[64][72];   // tree_out_bn bf16, +8 pad
  __shared__ float b1_lds[384];
  __shared__ float sb_lds[64];
  __shared__ float ob_lds[64];
  __shared__ float fcb_lds[256];

  const int tid  = (int)threadIdx.x;
  const int lane = tid & 63;
  const int w    = tid >> 6;      // wave 0..3
  const int tcol = lane & 15;     // fragment column lane
  const int g    = lane >> 4;     // k-group / row-group 0..3
  const int r0   = (int)blockIdx.x * 64;

  // ---- stage: x tile (64x256 f32 contiguous) -> bf16 A_lds; leaf; small tables ----
  {
    const float4* xs = (const float4*)(x + (size_t)r0 * 256);
    #pragma unroll
    for (int i = 0; i < 16; ++i) {
      int f = tid + 256 * i;            // float4 index 0..4095, coalesced
      float4 v = xs[f];
      int row = f >> 6, c4 = f & 63;
      unsigned int lo = (unsigned int)f2bf(v.x) | ((unsigned int)f2bf(v.y) << 16);
      unsigned int hi = (unsigned int)f2bf(v.z) | ((unsigned int)f2bf(v.w) << 16);
      unsigned int* p = (unsigned int*)&A_lds[row][c4 * 4];
      p[0] = lo; p[1] = hi;
    }
    #pragma unroll
    for (int i = 0; i < 4; ++i) {
      int f = tid + 256 * i;            // float4 index 0..1023
      float4 v = ((const float4*)leaf2)[f];
      int t = f >> 4, c4 = f & 15;
      *(float4*)&leaf_lds[t][c4 * 4] = v;
    }
    b1_lds[tid] = b1g[tid];
    if (tid < 128) b1_lds[256 + tid] = b1g[256 + tid];
    if (tid < 64) { sb_lds[tid] = sbg[tid]; ob_lds[tid] = obg[tid]; }
    fcb_lds[tid] = fc_b[tid];
  }
  __syncthreads();

  // ---- GEMM1: acc[rt][d] = x_tile(64x256) @ Wp'(256x384-slice), B direct from global(L2) ----
  floatx4 acc[4][6];
  #pragma unroll
  for (int rt = 0; rt < 4; ++rt)
    #pragma unroll
    for (int d = 0; d < 6; ++d) { acc[rt][d][0]=0.f; acc[rt][d][1]=0.f; acc[rt][d][2]=0.f; acc[rt][d][3]=0.f; }

  const unsigned short* Bb = Wp + (size_t)(w * 16 + tcol) * 256 + g * 8;

  short8 bA[6], bB[6];
  #pragma unroll
  for (int d = 0; d < 6; ++d) bA[d] = *(const short8*)(Bb + d * 16384);

  #pragma unroll 1
  for (int kp = 0; kp < 4; ++kp) {
    // prefetch odd k-step
    #pragma unroll
    for (int d = 0; d < 6; ++d) bB[d] = *(const short8*)(Bb + d * 16384 + (kp * 2 + 1) * 32);
    short8 a[4];
    #pragma unroll
    for (int rt = 0; rt < 4; ++rt)
      a[rt] = *(const short8*)&A_lds[rt * 16 + tcol][kp * 64 + g * 8];
    #pragma unroll
    for (int d = 0; d < 6; ++d)
      #pragma unroll
      for (int rt = 0; rt < 4; ++rt)
        acc[rt][d] = __builtin_amdgcn_mfma_f32_16x16x32_bf16(a[rt], bA[d], acc[rt][d], 0, 0, 0);
    if (kp < 3) {
      #pragma unroll
      for (int d = 0; d < 6; ++d) bA[d] = *(const short8*)(Bb + d * 16384 + (kp * 2 + 2) * 32);
    }
    #pragma unroll
    for (int rt = 0; rt < 4; ++rt)
      a[rt] = *(const short8*)&A_lds[rt * 16 + tcol][kp * 64 + 32 + g * 8];
    #pragma unroll
    for (int d = 0; d < 6; ++d)
      #pragma unroll
      for (int rt = 0; rt < 4; ++rt)
        acc[rt][d] = __builtin_amdgcn_mfma_f32_16x16x32_bf16(a[rt], bB[d], acc[rt][d], 0, 0, 0);
  }

  // ---- phase 2: sigmoid + oblivious-tree DP + BN, fully in registers ----
  const int tree = w * 16 + tcol;   // this lane's tree; 16 rows: rt*16 + g*4 + j
  float bp[6];
  #pragma unroll
  for (int d = 0; d < 6; ++d) bp[d] = b1_lds[d * 64 + tree];
  const float sbv = sb_lds[tree], obv = ob_lds[tree];

  // sigmoid(logit) = rcp(1 + exp2(-log2e*logit)); scaling pre-folded into Wp/b1
  #pragma unroll
  for (int rt = 0; rt < 4; ++rt)
    #pragma unroll
    for (int d = 0; d < 6; ++d)
      #pragma unroll
      for (int j = 0; j < 4; ++j) {
        float z = acc[rt][d][j] + bp[d];
        acc[rt][d][j] = __builtin_amdgcn_rcpf(1.0f + __builtin_amdgcn_exp2f(z));
      }

  float L[32], resLo[16];
  // low half: leaves 0..31 (bit5=0 => depth-0 weight (1-dec0)); DP levels use dec5..dec1
  #pragma unroll
  for (int c = 0; c < 8; ++c) {
    float4 v = *(const float4*)&leaf_lds[tree][c * 4];
    L[c*4+0] = v.x; L[c*4+1] = v.y; L[c*4+2] = v.z; L[c*4+3] = v.w;
  }
  #pragma unroll
  for (int rt = 0; rt < 4; ++rt)
    #pragma unroll
    for (int j = 0; j < 4; ++j) {
      float u[16];
      const float d5 = acc[rt][5][j];
      #pragma unroll
      for (int i = 0; i < 16; ++i) u[i] = fmaf(d5, L[2*i+1], L[2*i]);   // (a, delta) pairs
      const float d4 = acc[rt][4][j];
      #pragma unroll
      for (int i = 0; i < 8; ++i) u[i] = fmaf(d4, u[2*i+1] - u[2*i], u[2*i]);
      const float d3 = acc[rt][3][j];
      #pragma unroll
      for (int i = 0; i < 4; ++i) u[i] = fmaf(d3, u[2*i+1] - u[2*i], u[2*i]);
      const float d2 = acc[rt][2][j];
      #pragma unroll
      for (int i = 0; i < 2; ++i) u[i] = fmaf(d2, u[2*i+1] - u[2*i], u[2*i]);
      resLo[rt*4+j] = fmaf(acc[rt][1][j], u[1] - u[0], u[0]);
    }
  // high half + combine with dec0, BN affine, write bf16 to A2_lds
  #pragma unroll
  for (int c = 0; c < 8; ++c) {
    float4 v = *(const float4*)&leaf_lds[tree][32 + c * 4];
    L[c*4+0] = v.x; L[c*4+1] = v.y; L[c*4+2] = v.z; L[c*4+3] = v.w;
  }
  #pragma unroll
  for (int rt = 0; rt < 4; ++rt)
    #pragma unroll
    for (int j = 0; j < 4; ++j) {
      float u[16];
      const float d5 = acc[rt][5][j];
      #pragma unroll
      for (int i = 0; i < 16; ++i) u[i] = fmaf(d5, L[2*i+1], L[2*i]);
      const float d4 = acc[rt][4][j];
      #pragma unroll
      for (int i = 0; i < 8; ++i) u[i] = fmaf(d4, u[2*i+1] - u[2*i], u[2*i]);
      const float d3 = acc[rt][3][j];
      #pragma unroll
      for (int i = 0; i < 4; ++i) u[i] = fmaf(d3, u[2*i+1] - u[2*i], u[2*i]);
      const float d2 = acc[rt][2][j];
      #pragma unroll
      for (int i = 0; i < 2; ++i) u[i] = fmaf(d2, u[2*i+1] - u[2*i], u[2*i]);
      float hi_r = fmaf(acc[rt][1][j], u[1] - u[0], u[0]);
      float lo_r = resLo[rt*4+j];
      float to   = fmaf(acc[rt][0][j], hi_r - lo_r, lo_r);
      float vv   = fmaf(to, sbv, obv);
      A2_lds[rt * 16 + g * 4 + j][tree] = f2bf(vv);
    }
  __syncthreads();

  // ---- GEMM2: out(64x256-slice) = tree_out_bn(64x64) @ fc_w^T, + fc_b ----
  floatx4 acc2[4][4];
  #pragma unroll
  for (int rt = 0; rt < 4; ++rt)
    #pragma unroll
    for (int nt = 0; nt < 4; ++nt) { acc2[rt][nt][0]=0.f; acc2[rt][nt][1]=0.f; acc2[rt][nt][2]=0.f; acc2[rt][nt][3]=0.f; }

  #pragma unroll
  for (int kst = 0; kst < 2; ++kst) {
    short8 a2[4];
    #pragma unroll
    for (int rt = 0; rt < 4; ++rt)
      a2[rt] = *(const short8*)&A2_lds[rt * 16 + tcol][kst * 32 + g * 8];
    #pragma unroll
    for (int nt = 0; nt < 4; ++nt) {
      short8 b2 = *(const short8*)(fcw + (size_t)(w * 64 + nt * 16 + tcol) * 64 + kst * 32 + g * 8);
      #pragma unroll
      for (int rt = 0; rt < 4; ++rt)
        acc2[rt][nt] = __builtin_amdgcn_mfma_f32_16x16x32_bf16(a2[rt], b2, acc2[rt][nt], 0, 0, 0);
    }
  }

  #pragma unroll
  for (int nt = 0; nt < 4; ++nt) {
    const int col = w * 64 + nt * 16 + tcol;
    const float bv = fcb_lds[col];
    #pragma unroll
    for (int rt = 0; rt < 4; ++rt)
      #pragma unroll
      for (int j = 0; j < 4; ++j)
        out[(size_t)(r0 + rt * 16 + g * 4 + j) * 256 + col] = acc2[rt][nt][j] + bv;
  }
}

extern "C" void kernel_launch(void* const* d_in, const int* in_sizes, int n_in,
                              void* d_out, int out_size, void* d_ws, size_t ws_size,
                              hipStream_t stream) {
  const float* x        = (const float*)d_in[0];
  const float* W_dec    = (const float*)d_in[1];
  const float* b_dec    = (const float*)d_in[2];
  const float* leaf     = (const float*)d_in[3];
  const float* bn_gamma = (const float*)d_in[4];
  const float* bn_beta  = (const float*)d_in[5];
  const float* bn_mean  = (const float*)d_in[6];
  const float* bn_var   = (const float*)d_in[7];
  const float* fc_w     = (const float*)d_in[8];
  const float* fc_b     = (const float*)d_in[9];
  float* out = (float*)d_out;

  char* ws = (char*)d_ws;
  unsigned short* Wp  = (unsigned short*)(ws);            // 196608 B
  unsigned short* fcw = (unsigned short*)(ws + 196608);   // 32768 B
  float* leaf2 = (float*)(ws + 229376);                   // 16384 B
  float* b1    = (float*)(ws + 245760);                   // 1536 B
  float* sb    = (float*)(ws + 247296);                   // 256 B
  float* ob    = (float*)(ws + 247552);                   // 256 B

  // total prep work items: 98304 + 16384 + 2048 + 384 + 64 = 117184 -> 458 blocks
  prep_kernel<<<458, 256, 0, stream>>>(W_dec, b_dec, leaf, bn_gamma, bn_beta,
                                       bn_mean, bn_var, fc_w,
                                       Wp, fcw, leaf2, b1, sb, ob);
  node_main<<<512, 256, 0, stream>>>(x, Wp, fcw, leaf2, b1, sb, ob, fc_b, out);
}